// Round 1
// baseline (113.279 us; speedup 1.0000x reference)
//
#include <hip/hip_runtime.h>

// Haar scaling coefficient s = 1/sqrt(2), matching float32(lpf[0]) exactly.
#define HAAR_S 0.70710678118654752440f

// Geometry of the fixed problem: [B=64, H=512, W=512, C=1] fp32.
// Each thread processes TWO horizontal 2x2 blocks:
//   reads  : float4 from row 2i and row 2i+1 (16B/lane, fully coalesced)
//   writes : float2 into each of the 4 subband quadrants (8B/lane, coalesced)
__global__ __launch_bounds__(256) void haar_dwt2d_kernel(
    const float* __restrict__ x, float* __restrict__ out, int batch)
{
    const int J = 128;   // pairs-of-blocks per row:  W/2 / 2
    const int I = 256;   // block rows: H/2
    int tid  = blockIdx.x * blockDim.x + threadIdx.x;
    int j4   = tid % J;          // covers output cols 2*j4, 2*j4+1
    int rest = tid / J;
    int i    = rest % I;         // output row within quadrant
    int b    = rest / I;
    if (b >= batch) return;

    const float* xb = x + (size_t)b * (512 * 512);
    const float4 r0 = *reinterpret_cast<const float4*>(xb + (size_t)(2 * i)     * 512 + 4 * j4);
    const float4 r1 = *reinterpret_cast<const float4*>(xb + (size_t)(2 * i + 1) * 512 + 4 * j4);

    // Block 0 butterfly (match reference op order for bit-close rounding)
    float a0 = HAAR_S * (r0.x + r0.y), d0 = HAAR_S * (r0.x - r0.y);
    float a1 = HAAR_S * (r1.x + r1.y), d1 = HAAR_S * (r1.x - r1.y);
    float ll0 = HAAR_S * (a0 + a1), lh0 = HAAR_S * (a0 - a1);
    float hl0 = HAAR_S * (d0 + d1), hh0 = HAAR_S * (d0 - d1);

    // Block 1
    float a2 = HAAR_S * (r0.z + r0.w), d2 = HAAR_S * (r0.z - r0.w);
    float a3 = HAAR_S * (r1.z + r1.w), d3 = HAAR_S * (r1.z - r1.w);
    float ll1 = HAAR_S * (a2 + a3), lh1 = HAAR_S * (a2 - a3);
    float hl1 = HAAR_S * (d2 + d3), hh1 = HAAR_S * (d2 - d3);

    float* ob = out + (size_t)b * (512 * 512);
    int c = 2 * j4;
    // Quadrant layout: [[ll, hl], [lh, hh]]
    *reinterpret_cast<float2*>(ob + (size_t)i         * 512 + c      ) = make_float2(ll0, ll1);
    *reinterpret_cast<float2*>(ob + (size_t)i         * 512 + c + 256) = make_float2(hl0, hl1);
    *reinterpret_cast<float2*>(ob + (size_t)(i + 256) * 512 + c      ) = make_float2(lh0, lh1);
    *reinterpret_cast<float2*>(ob + (size_t)(i + 256) * 512 + c + 256) = make_float2(hh0, hh1);
}

extern "C" void kernel_launch(void* const* d_in, const int* in_sizes, int n_in,
                              void* d_out, int out_size, void* d_ws, size_t ws_size,
                              hipStream_t stream) {
    const float* x = (const float*)d_in[0];
    float* out = (float*)d_out;
    int batch = in_sizes[0] / (512 * 512);   // 64 for this problem
    int total_threads = batch * 256 * 128;   // one thread per 2 output-blocks
    int block = 256;
    int grid = (total_threads + block - 1) / block;   // 8192 blocks
    haar_dwt2d_kernel<<<grid, block, 0, stream>>>(x, out, batch);
}